// Round 5
// baseline (116.906 us; speedup 1.0000x reference)
//
#include <hip/hip_runtime.h>
#include <cstdint>
#include <cstddef>

#define Bn 64
#define Sn 512
#define Hn 768
#define Tn 50
#define CH 32   // scan chunk length (steps)
#define NCH 16  // max chunks per sequence = ceil((Sn-1)/CH)

typedef short short8 __attribute__((ext_vector_type(8)));
typedef float floatx4 __attribute__((ext_vector_type(4)));

__device__ __forceinline__ uint32_t rne_bf16(float x) {
  uint32_t u = __float_as_uint(x);
  return (u + 0x7FFFu + ((u >> 16) & 1u)) >> 16;
}
__device__ __forceinline__ uint32_t pack2(float a, float b) {
  return rne_bf16(a) | (rne_bf16(b) << 16);
}
__device__ __forceinline__ float rdlane(float v, int i) {
  return __uint_as_float(__builtin_amdgcn_readlane(__float_as_uint(v), i));
}

// ---------------- Kernel 1: emissions via MFMA, W packed in-block ----------
// Block = 4 waves, 64 rows (batch bb, s-chunk c). Gate: prefix-mask property
// => chunk needed iff mask[bb][c*64]. Each block packs all of W into its own
// LDS as bf16 MFMA fragments (L2-hot scattered reads, ~1 us, overlapped),
// then runs the r3 MFMA loop with wave-private swizzled A staging.
// Block 0 also zeroes the 64 per-batch arrival counters for kernel 2.
#define BK 64
__global__ __launch_bounds__(256) void emissions_kernel(
    const float* __restrict__ hidden, const float* __restrict__ W,
    const float* __restrict__ bias, const int* __restrict__ mask,
    float* __restrict__ em, int* __restrict__ counters) {
  const int blk = blockIdx.x;
  const int tid = threadIdx.x;
  if (blk == 0 && tid < 64) counters[tid] = 0;  // before gate: block 0 is
                                                // always active (len >= 1)
  const int bb = blk >> 3, c = blk & 3 + (blk & 7 & ~3);  // placeholder
  // (computed properly below; kept simple)
  const int bb2 = blk >> 3, cc = blk & 7;
  if (mask[bb2 * Sn + cc * 64] == 0) return;  // rows >= len: never read

  const int lane = tid & 63;
  const int w = tid >> 6;
  const int g = lane >> 4;
  const int li = lane & 15;
  const int row0 = blk * 64;

  __shared__ uint4 wlds[96 * 64];      // 98304 B: packed W fragments
  __shared__ char lds_raw[64 * 128];   // 8192 B: swizzled A tile

  const float* hbase = hidden + (size_t)row0 * Hn;

  // issue first A prefetch early (HBM latency hides under the W pack)
  float4 pf[4];
#pragma unroll
  for (int k = 0; k < 4; ++k)
    pf[k] = *(const float4*)(hbase + (size_t)(w * 16 + 4 * k + g) * Hn + li * 4);

  // ---- pack W -> LDS fragments (same map as r4 prep kernel) ----
#pragma unroll
  for (int it = 0; it < 24; ++it) {
    const int idx = tid + it * 256;  // [0, 6144)
    const int f = idx >> 6;          // 0..95
    const int l = idx & 63;
    const int ks = f >> 2, nt = f & 3;
    const int col = nt * 16 + (l & 15);
    const int k0 = ks * 32 + (l >> 4) * 8;
    float v[8];
#pragma unroll
    for (int j = 0; j < 8; ++j)
      v[j] = (col < Tn) ? W[(size_t)(k0 + j) * Tn + col] : 0.f;
    uint4 d;
    d.x = pack2(v[0], v[1]);
    d.y = pack2(v[2], v[3]);
    d.z = pack2(v[4], v[5]);
    d.w = pack2(v[6], v[7]);
    wlds[idx] = d;
  }
  __syncthreads();

  floatx4 acc[4];
#pragma unroll
  for (int nt = 0; nt < 4; ++nt) acc[nt] = (floatx4)0.f;

  for (int ch = 0; ch < Hn / BK; ++ch) {
#pragma unroll
    for (int k = 0; k < 4; ++k) {
      const int r = w * 16 + 4 * k + g;
      const uint32_t b0 = pack2(pf[k].x, pf[k].y);
      const uint32_t b1 = pack2(pf[k].z, pf[k].w);
      const int byteoff = r * 128 + ((li * 8) ^ ((r & 7) << 4));
      *(uint2*)(lds_raw + byteoff) = make_uint2(b0, b1);
    }
    if (ch + 1 < Hn / BK) {
      const int kc = (ch + 1) * BK;
#pragma unroll
      for (int k = 0; k < 4; ++k)
        pf[k] = *(const float4*)(hbase + (size_t)(w * 16 + 4 * k + g) * Hn + kc +
                                 li * 4);
    }
    asm volatile("s_waitcnt lgkmcnt(0)" ::: "memory");
#pragma unroll
    for (int ks = 0; ks < 2; ++ks) {
      const int r = w * 16 + li;
      const int kb = ks * 64 + g * 16;
      const short8 af =
          *(const short8*)(lds_raw + r * 128 + (kb ^ ((r & 7) << 4)));
      const int ksg = ch * 2 + ks;
#pragma unroll
      for (int nt = 0; nt < 4; ++nt) {
        const short8 bf = *(const short8*)&wlds[(ksg * 4 + nt) * 64 + lane];
        acc[nt] =
            __builtin_amdgcn_mfma_f32_16x16x32_bf16(af, bf, acc[nt], 0, 0, 0);
      }
    }
  }
#pragma unroll
  for (int nt = 0; nt < 4; ++nt) {
    const int col = nt * 16 + li;
    if (col < Tn) {
      const float bs = bias[col];
#pragma unroll
      for (int r = 0; r < 4; ++r) {
        const int row = row0 + w * 16 + g * 4 + r;
        em[(size_t)row * Tn + col] = acc[nt][r] + bs;
      }
    }
  }
}

// ---------------- Kernel 2: chunked scans + last-block stitch ----------------
// Grid = Bn*NCH*2 single-wave blocks. Every block (active or not) arrives at
// counters[b]; the 32nd arrival runs the stitch. Scan math identical to r4.
__global__ __launch_bounds__(64) void scan_stitch_kernel(
    const float* __restrict__ em, const float* __restrict__ startT,
    const float* __restrict__ endT, const float* __restrict__ trans,
    const int* __restrict__ tag, const int* __restrict__ mask,
    float* __restrict__ fvec, float* __restrict__ gvec,
    float* __restrict__ Lf, float* __restrict__ numpart,
    int* __restrict__ counters, float* __restrict__ out) {
  const int blk = blockIdx.x;
  const int b = blk >> 5;              // 32 tasks per batch
  const int c = (blk >> 1) & (NCH - 1);
  const int dir = blk & 1;             // 0 = forward (f), 1 = backward (g)
  const int lane = threadIdx.x;
  const int jc = lane < Tn ? lane : 0;
  const bool live = lane < Tn;
  const float* emb = em + (size_t)b * Sn * Tn;

  // length (from mask; no lenbuf)
  int len = 0;
  for (int t = lane; t < Sn; t += 64) len += mask[b * Sn + t];
#pragma unroll
  for (int off = 1; off < 64; off <<= 1) len += __shfl_xor(len, off);

  const int t0 = 1 + c * CH;
  const bool active = (t0 < len) && !(dir && c == 0);

  if (active) {
    const int t1 = (t0 + CH < len) ? t0 + CH : len;
    const int L = t1 - t0;

    if (!dir) {  // chunk numerator partial; lane = timestep
      float npv = 0.f;
      if (lane < L) {
        const int t = t0 + lane;
        const int tp = tag[b * Sn + t - 1], tc = tag[b * Sn + t];
        npv = trans[tp * Tn + tc] + emb[(size_t)t * Tn + tc];
      }
#pragma unroll
      for (int off = 1; off < 64; off <<= 1) npv += __shfl_xor(npv, off);
      if (lane == 0) numpart[b * NCH + c] = npv;
    }

    float e[Tn];
#pragma unroll
    for (int i = 0; i < Tn; ++i) {
      e[i] = __expf(dir ? trans[jc * Tn + i] : trans[i * Tn + jc]);
      asm volatile("" : "+v"(e[i]));  // pin in VGPR, block remat/spill
    }

    float Cacc = 0.f;
    float q;
    if (!dir)
      q = live ? (c == 0 ? __expf(startT[jc] + emb[jc]) : 1.f) : 0.f;
    else
      q = live ? 1.f : 0.f;

#define T_OF(k) (dir ? (t1 - 1 - (k)) : (t0 + (k)))
    float ld1 = emb[(size_t)T_OF(0) * Tn + jc];
    const float ld2 = emb[(size_t)T_OF(L > 1 ? 1 : 0) * Tn + jc];
    float ee = live ? __expf(ld1) : 0.f;
    ld1 = ld2;

    for (int k = 0; k < L; ++k) {
      const float ee_cur = ee;
      const int kn = (k + 2 < L) ? k + 2 : L - 1;
      const float ldn = emb[(size_t)T_OF(kn) * Tn + jc];
      ee = live ? __expf(ld1) : 0.f;
      ld1 = ldn;

      const float x = dir ? ee_cur * q : q;
      float s0 = 0.f, s1 = 0.f, s2 = 0.f, s3 = 0.f;
#pragma unroll
      for (int i = 0; i < 48; i += 4) {
        s0 = fmaf(rdlane(x, i + 0), e[i + 0], s0);
        s1 = fmaf(rdlane(x, i + 1), e[i + 1], s1);
        s2 = fmaf(rdlane(x, i + 2), e[i + 2], s2);
        s3 = fmaf(rdlane(x, i + 3), e[i + 3], s3);
      }
      s0 = fmaf(rdlane(x, 48), e[48], s0);
      s1 = fmaf(rdlane(x, 49), e[49], s1);
      const float s = (s0 + s1) + (s2 + s3);
      q = dir ? s : ee_cur * s;

      if ((k & 7) == 7) {
        float M = q;
#pragma unroll
        for (int off = 1; off < 64; off <<= 1) M = fmaxf(M, __shfl_xor(M, off));
        const float r = __builtin_amdgcn_rcpf(M);
        q *= r;
        Cacc -= __logf(r);
      }
    }
#undef T_OF

    float M = q;
#pragma unroll
    for (int off = 1; off < 64; off <<= 1) M = fmaxf(M, __shfl_xor(M, off));
    const float r = __builtin_amdgcn_rcpf(M);
    const float qn = live ? q * r : 0.f;
    Cacc -= __logf(r);
    if (dir) {
      gvec[((size_t)b * NCH + c) * 64 + lane] = qn;
    } else {
      fvec[((size_t)b * NCH + c) * 64 + lane] = qn;
      if (lane == 0) Lf[b * NCH + c] = Cacc;
    }
  }

  // ---- arrive; last of the batch's 32 blocks stitches ----
  __threadfence();
  int old = 0;
  if (lane == 0) old = atomicAdd(&counters[b], 1);
  old = __shfl(old, 0);
  if (old != 31) return;
  __threadfence();

  const int C = (len - 1 + CH - 1) / CH;

  float np = (lane < C) ? numpart[b * NCH + lane] : 0.f;
#pragma unroll
  for (int off = 1; off < 64; off <<= 1) np += __shfl_xor(np, off);
  const int tg0 = tag[b * Sn];
  const int tgl = tag[b * Sn + len - 1];
  np += startT[tg0] + emb[tg0] + endT[tgl];

  float den;
  if (C == 0) {  // len == 1
    float v = live ? (startT[jc] + emb[jc] + endT[jc]) : -INFINITY;
    float M = v;
#pragma unroll
    for (int off = 1; off < 64; off <<= 1) M = fmaxf(M, __shfl_xor(M, off));
    float s = __expf(v - M);
#pragma unroll
    for (int off = 1; off < 64; off <<= 1) s += __shfl_xor(s, off);
    den = M + __logf(s);
  } else {
    const float ev = live ? __expf(endT[jc]) : 0.f;
    float d = fvec[((size_t)b * NCH + C - 1) * 64 + lane] * ev;
#pragma unroll
    for (int off = 1; off < 64; off <<= 1) d += __shfl_xor(d, off);
    den = Lf[b * NCH + C - 1] + __logf(d);
    for (int c2 = 1; c2 < C; ++c2) {
      const float g = gvec[((size_t)b * NCH + c2) * 64 + lane];
      const float f = fvec[((size_t)b * NCH + c2 - 1) * 64 + lane];
      float dot = g * f;
      float gs = g;
#pragma unroll
      for (int off = 1; off < 64; off <<= 1) {
        dot += __shfl_xor(dot, off);
        gs += __shfl_xor(gs, off);
      }
      den += Lf[b * NCH + c2 - 1] + __logf(dot) - __logf(gs);
    }
  }
  if (lane == 0) out[b] = den - np;
}

extern "C" void kernel_launch(void* const* d_in, const int* in_sizes, int n_in,
                              void* d_out, int out_size, void* d_ws,
                              size_t ws_size, hipStream_t stream) {
  const float* hidden = (const float*)d_in[0];
  const float* W = (const float*)d_in[1];
  const float* bias = (const float*)d_in[2];
  const float* startT = (const float*)d_in[3];
  const float* endT = (const float*)d_in[4];
  const float* trans = (const float*)d_in[5];
  const int* tag = (const int*)d_in[6];
  const int* mask = (const int*)d_in[7];
  float* out = (float*)d_out;

  // ws layout
  char* ws = (char*)d_ws;
  float* em = (float*)ws;                      // 6,553,600 B
  float* fvec = (float*)(ws + 6553600);        //   262,144 B
  float* gvec = (float*)(ws + 6815744);        //   262,144 B
  float* Lf = (float*)(ws + 7077888);          //     4,096 B
  float* numpart = (float*)(ws + 7081984);     //     4,096 B
  int* counters = (int*)(ws + 7086080);        //       256 B

  emissions_kernel<<<(Bn * Sn) / 64, 256, 0, stream>>>(hidden, W, bias, mask,
                                                       em, counters);
  scan_stitch_kernel<<<Bn * NCH * 2, 64, 0, stream>>>(
      em, startT, endT, trans, tag, mask, fvec, gvec, Lf, numpart, counters,
      out);
}

// Round 6
// 53.156 us; speedup vs baseline: 2.1993x; 2.1993x over previous
//
#include <hip/hip_runtime.h>
#include <cstdint>
#include <cstddef>

#define Bn 64
#define Sn 512
#define Hn 768
#define Tn 50
#define CH 32   // scan chunk length (steps)
#define NCH 16  // max chunks per sequence = ceil((Sn-1)/CH)
#define EP 52   // padded row stride for exp(trans) tables (208 B, 16B-aligned)

typedef short short8 __attribute__((ext_vector_type(8)));
typedef float floatx4 __attribute__((ext_vector_type(4)));

__device__ __forceinline__ uint32_t rne_bf16(float x) {
  uint32_t u = __float_as_uint(x);
  return (u + 0x7FFFu + ((u >> 16) & 1u)) >> 16;
}
__device__ __forceinline__ uint32_t pack2(float a, float b) {
  return rne_bf16(a) | (rne_bf16(b) << 16);
}
__device__ __forceinline__ float rdlane(float v, int i) {
  return __uint_as_float(__builtin_amdgcn_readlane(__float_as_uint(v), i));
}

// ------ Kernel 0: prep — lengths + W fragment pack + exp(trans) tables ------
__global__ __launch_bounds__(256) void prep_kernel(
    const float* __restrict__ W, const float* __restrict__ trans,
    const int* __restrict__ mask, uint32_t* __restrict__ wfrag,
    int* __restrict__ lenbuf, float* __restrict__ Ee,
    float* __restrict__ EeT) {
  const int blk = blockIdx.x;
  const int tid = threadIdx.x;
  if (blk < 64) {
    if (tid < 64) {
      int s = 0;
      for (int t = tid; t < Sn; t += 64) s += mask[blk * Sn + t];
#pragma unroll
      for (int off = 1; off < 64; off <<= 1) s += __shfl_xor(s, off);
      if (tid == 0) lenbuf[blk] = s;
    }
    return;
  }
  if (blk == 88) {  // exp(trans) and transpose, padded stride EP
    for (int gid = tid; gid < Tn * Tn; gid += 256) {
      const int r = gid / Tn, cl = gid - r * Tn;
      const float v = __expf(trans[gid]);
      Ee[r * EP + cl] = v;
      EeT[cl * EP + r] = v;
    }
    return;
  }
  const int gid = (blk - 64) * 256 + tid;  // [0, 6144)
  const int f = gid >> 6;                  // 0..95
  const int l = gid & 63;
  const int ks = f >> 2, nt = f & 3;
  const int col = nt * 16 + (l & 15);
  const int k0 = ks * 32 + (l >> 4) * 8;
  float v[8];
#pragma unroll
  for (int j = 0; j < 8; ++j)
    v[j] = (col < Tn) ? W[(size_t)(k0 + j) * Tn + col] : 0.f;
  uint4 d;
  d.x = pack2(v[0], v[1]);
  d.y = pack2(v[2], v[3]);
  d.z = pack2(v[4], v[5]);
  d.w = pack2(v[6], v[7]);
  ((uint4*)wfrag)[gid] = d;
}

// ------ Kernel 1: emissions via MFMA, 2-deep ping-pong prefetch ------
#define BK 64
__global__ __launch_bounds__(256, 1) void emissions_kernel(
    const float* __restrict__ hidden, const uint32_t* __restrict__ wfrag,
    const float* __restrict__ bias, const int* __restrict__ lenbuf,
    float* __restrict__ em) {
  const int blk = blockIdx.x;
  const int bb = blk >> 3, cc = blk & 7;
  if (cc * 64 >= lenbuf[bb]) return;  // rows never read by CRF
  const int tid = threadIdx.x;
  const int lane = tid & 63;
  const int w = tid >> 6;
  const int g = lane >> 4;
  const int li = lane & 15;
  const int row0 = blk * 64;
  __shared__ char lds_raw[64 * 128];

  floatx4 acc[4];
#pragma unroll
  for (int nt = 0; nt < 4; ++nt) acc[nt] = (floatx4)0.f;

  const float* hbase = hidden + (size_t)row0 * Hn;
  const short8* wf = (const short8*)wfrag;

#define LOADCH(dst, ch)                                                       \
  _Pragma("unroll") for (int k = 0; k < 4; ++k) dst[k] =                      \
      *(const float4*)(hbase + (size_t)(w * 16 + 4 * k + g) * Hn + (ch)*BK +  \
                       li * 4);

#define WRITELDS(src)                                                         \
  _Pragma("unroll") for (int k = 0; k < 4; ++k) {                             \
    const int r = w * 16 + 4 * k + g;                                         \
    const uint32_t b0 = pack2(src[k].x, src[k].y);                            \
    const uint32_t b1 = pack2(src[k].z, src[k].w);                            \
    const int byteoff = r * 128 + ((li * 8) ^ ((r & 7) << 4));                \
    *(uint2*)(lds_raw + byteoff) = make_uint2(b0, b1);                        \
  }

#define COMPUTE(ch)                                                           \
  _Pragma("unroll") for (int ks = 0; ks < 2; ++ks) {                          \
    const int r = w * 16 + li;                                                \
    const int kb = ks * 64 + g * 16;                                          \
    const short8 af =                                                         \
        *(const short8*)(lds_raw + r * 128 + (kb ^ ((r & 7) << 4)));          \
    const int ksg = (ch)*2 + ks;                                              \
    _Pragma("unroll") for (int nt = 0; nt < 4; ++nt) {                        \
      const short8 bf = wf[(ksg * 4 + nt) * 64 + lane];                       \
      acc[nt] =                                                               \
          __builtin_amdgcn_mfma_f32_16x16x32_bf16(af, bf, acc[nt], 0, 0, 0);  \
    }                                                                         \
  }

  float4 pfA[4], pfB[4];
  LOADCH(pfA, 0)
  LOADCH(pfB, 1)
#pragma unroll
  for (int chp = 0; chp < Hn / BK / 2; ++chp) {
    const int ch = 2 * chp;
    WRITELDS(pfA)
    if (ch + 2 < Hn / BK) LOADCH(pfA, ch + 2)
    COMPUTE(ch)
    WRITELDS(pfB)
    if (ch + 3 < Hn / BK) LOADCH(pfB, ch + 3)
    COMPUTE(ch + 1)
  }
#undef LOADCH
#undef WRITELDS
#undef COMPUTE

#pragma unroll
  for (int nt = 0; nt < 4; ++nt) {
    const int col = nt * 16 + li;
    if (col < Tn) {
      const float bs = bias[col];
#pragma unroll
      for (int r = 0; r < 4; ++r) {
        const int row = row0 + w * 16 + g * 4 + r;
        em[(size_t)row * Tn + col] = acc[nt][r] + bs;
      }
    }
  }
}

// ------ Kernel 2: chunked scans (f forward / g backward) ------
// __launch_bounds__(64, 1): min-waves/EU = 1 so the VGPR cap is 512 and
// e[50] stays in registers (r5's VGPR_Count=40 proved it was in scratch).
__global__ __launch_bounds__(64, 1) void scan_kernel(
    const float* __restrict__ em, const float* __restrict__ startT,
    const float* __restrict__ trans, const float* __restrict__ Ee,
    const float* __restrict__ EeT, const int* __restrict__ tag,
    const int* __restrict__ lenbuf, float* __restrict__ fvec,
    float* __restrict__ gvec, float* __restrict__ Lf,
    float* __restrict__ numpart) {
  const int blk = blockIdx.x;
  const int b = blk >> 5;
  const int c = (blk >> 1) & (NCH - 1);
  const int dir = blk & 1;  // 0 = forward (f), 1 = backward (g)
  const int len = lenbuf[b];
  const int t0 = 1 + c * CH;
  if (t0 >= len) return;
  if (dir && c == 0) return;
  const int t1 = (t0 + CH < len) ? t0 + CH : len;
  const int L = t1 - t0;
  const int lane = threadIdx.x;
  const int jc = lane < Tn ? lane : 0;
  const bool live = lane < Tn;
  const float* emb = em + (size_t)b * Sn * Tn;

  if (!dir) {  // chunk numerator partial; lane = timestep
    float npv = 0.f;
    if (lane < L) {
      const int t = t0 + lane;
      const int tp = tag[b * Sn + t - 1], tc = tag[b * Sn + t];
      npv = trans[tp * Tn + tc] + emb[(size_t)t * Tn + tc];
    }
#pragma unroll
    for (int off = 1; off < 64; off <<= 1) npv += __shfl_xor(npv, off);
    if (lane == 0) numpart[b * NCH + c] = npv;
  }

  // e[i]: f needs E[i][jc] = EeT row jc; g needs E[jc][i] = Ee row jc.
  // Rows are contiguous, EP*4 = 208 B stride, 16B-aligned -> dwordx4 loads.
  const float* ebase = (dir ? Ee : EeT) + jc * EP;
  float e[Tn];
#pragma unroll
  for (int i = 0; i < Tn; ++i) e[i] = ebase[i];

  float Cacc = 0.f;
  float q;
  if (!dir)
    q = live ? (c == 0 ? __expf(startT[jc] + emb[jc]) : 1.f) : 0.f;
  else
    q = live ? 1.f : 0.f;

#define T_OF(k) (dir ? (t1 - 1 - (k)) : (t0 + (k)))
  float ld1 = emb[(size_t)T_OF(0) * Tn + jc];
  const float ld2 = emb[(size_t)T_OF(L > 1 ? 1 : 0) * Tn + jc];
  float ee = live ? __expf(ld1) : 0.f;
  ld1 = ld2;

  for (int k = 0; k < L; ++k) {
    const float ee_cur = ee;
    const int kn = (k + 2 < L) ? k + 2 : L - 1;
    const float ldn = emb[(size_t)T_OF(kn) * Tn + jc];
    ee = live ? __expf(ld1) : 0.f;
    ld1 = ldn;

    const float x = dir ? ee_cur * q : q;  // g pre-multiplies by D_t
    float s0 = 0.f, s1 = 0.f, s2 = 0.f, s3 = 0.f;
#pragma unroll
    for (int i = 0; i < 48; i += 4) {
      s0 = fmaf(rdlane(x, i + 0), e[i + 0], s0);
      s1 = fmaf(rdlane(x, i + 1), e[i + 1], s1);
      s2 = fmaf(rdlane(x, i + 2), e[i + 2], s2);
      s3 = fmaf(rdlane(x, i + 3), e[i + 3], s3);
    }
    s0 = fmaf(rdlane(x, 48), e[48], s0);
    s1 = fmaf(rdlane(x, 49), e[49], s1);
    const float s = (s0 + s1) + (s2 + s3);
    q = dir ? s : ee_cur * s;  // f post-multiplies by D_t

    if ((k & 7) == 7) {
      float M = q;
#pragma unroll
      for (int off = 1; off < 64; off <<= 1) M = fmaxf(M, __shfl_xor(M, off));
      const float r = __builtin_amdgcn_rcpf(M);
      q *= r;
      Cacc -= __logf(r);
    }
  }
#undef T_OF

  float M = q;
#pragma unroll
  for (int off = 1; off < 64; off <<= 1) M = fmaxf(M, __shfl_xor(M, off));
  const float r = __builtin_amdgcn_rcpf(M);
  const float qn = live ? q * r : 0.f;
  Cacc -= __logf(r);
  if (dir) {
    gvec[((size_t)b * NCH + c) * 64 + lane] = qn;
  } else {
    fvec[((size_t)b * NCH + c) * 64 + lane] = qn;
    if (lane == 0) Lf[b * NCH + c] = Cacc;
  }
}

// ------ Kernel 3: stitch — rank-1 chain + numerator ------
__global__ __launch_bounds__(64) void stitch_kernel(
    const float* __restrict__ em, const float* __restrict__ startT,
    const float* __restrict__ endT, const int* __restrict__ tag,
    const int* __restrict__ lenbuf, const float* __restrict__ fvec,
    const float* __restrict__ gvec, const float* __restrict__ Lf,
    const float* __restrict__ numpart, float* __restrict__ out) {
  const int b = blockIdx.x;
  const int lane = threadIdx.x;
  const int len = lenbuf[b];
  const int C = (len - 1 + CH - 1) / CH;
  const int jc = lane < Tn ? lane : 0;
  const bool live = lane < Tn;
  const float* emb = em + (size_t)b * Sn * Tn;

  float np = (lane < C) ? numpart[b * NCH + lane] : 0.f;
#pragma unroll
  for (int off = 1; off < 64; off <<= 1) np += __shfl_xor(np, off);
  const int tg0 = tag[b * Sn];
  const int tgl = tag[b * Sn + len - 1];
  np += startT[tg0] + emb[tg0] + endT[tgl];

  float den;
  if (C == 0) {  // len == 1
    float v = live ? (startT[jc] + emb[jc] + endT[jc]) : -INFINITY;
    float M = v;
#pragma unroll
    for (int off = 1; off < 64; off <<= 1) M = fmaxf(M, __shfl_xor(M, off));
    float s = __expf(v - M);
#pragma unroll
    for (int off = 1; off < 64; off <<= 1) s += __shfl_xor(s, off);
    den = M + __logf(s);
  } else {
    const float ev = live ? __expf(endT[jc]) : 0.f;
    float d = fvec[((size_t)b * NCH + C - 1) * 64 + lane] * ev;
#pragma unroll
    for (int off = 1; off < 64; off <<= 1) d += __shfl_xor(d, off);
    den = Lf[b * NCH + C - 1] + __logf(d);
    for (int c2 = 1; c2 < C; ++c2) {
      const float g = gvec[((size_t)b * NCH + c2) * 64 + lane];
      const float f = fvec[((size_t)b * NCH + c2 - 1) * 64 + lane];
      float dot = g * f;
      float gs = g;
#pragma unroll
      for (int off = 1; off < 64; off <<= 1) {
        dot += __shfl_xor(dot, off);
        gs += __shfl_xor(gs, off);
      }
      den += Lf[b * NCH + c2 - 1] + __logf(dot) - __logf(gs);
    }
  }
  if (lane == 0) out[b] = den - np;
}

extern "C" void kernel_launch(void* const* d_in, const int* in_sizes, int n_in,
                              void* d_out, int out_size, void* d_ws,
                              size_t ws_size, hipStream_t stream) {
  const float* hidden = (const float*)d_in[0];
  const float* W = (const float*)d_in[1];
  const float* bias = (const float*)d_in[2];
  const float* startT = (const float*)d_in[3];
  const float* endT = (const float*)d_in[4];
  const float* trans = (const float*)d_in[5];
  const int* tag = (const int*)d_in[6];
  const int* mask = (const int*)d_in[7];
  float* out = (float*)d_out;

  // ws layout (16B-aligned offsets)
  char* ws = (char*)d_ws;
  float* em = (float*)ws;                   // 6,553,600 B
  uint32_t* wfrag = (uint32_t*)(ws + 6553600);  //  98,304 B
  int* lenbuf = (int*)(ws + 6651904);           //     256 B
  float* Ee = (float*)(ws + 6652160);           //  10,816 B
  float* EeT = (float*)(ws + 6662976);          //  10,816 B
  float* fvec = (float*)(ws + 6673792);         // 262,144 B
  float* gvec = (float*)(ws + 6935936);         // 262,144 B
  float* Lf = (float*)(ws + 7198080);           //   4,096 B
  float* numpart = (float*)(ws + 7202176);      //   4,096 B

  prep_kernel<<<89, 256, 0, stream>>>(W, trans, mask, wfrag, lenbuf, Ee, EeT);
  emissions_kernel<<<(Bn * Sn) / 64, 256, 0, stream>>>(hidden, wfrag, bias,
                                                       lenbuf, em);
  scan_kernel<<<Bn * NCH * 2, 64, 0, stream>>>(em, startT, trans, Ee, EeT, tag,
                                               lenbuf, fvec, gvec, Lf, numpart);
  stitch_kernel<<<Bn, 64, 0, stream>>>(em, startT, endT, tag, lenbuf, fvec,
                                       gvec, Lf, numpart, out);
}